// Round 10
// baseline (197.024 us; speedup 1.0000x reference)
//
#include <hip/hip_runtime.h>
#include <cstddef>

#define TT 64  // timesteps

#define RFL(x) __builtin_amdgcn_readfirstlane(x)

typedef unsigned long long u64;

// ---------------- CUBA LIF step helpers ----------------
__device__ __forceinline__ void scanc(float& c, float& v, float& z) {
    c = fmaf(0.7f, c, z);
    v = fmaf(0.75f, v, c);
    float s = (v >= 1.0f) ? 1.0f : 0.0f;
    v = (v >= 1.0f) ? 0.0f : v;
    z = s;
}
__device__ __forceinline__ void scan4(float& c, float& v, float4& a) {
    scanc(c, v, a.x); scanc(c, v, a.y); scanc(c, v, a.z); scanc(c, v, a.w);
}
__device__ __forceinline__ float bit2f(u64 m, int t) {
    return (float)((m >> t) & 1ULL);  // exactly 0.0f or 1.0f
}

// ---------------- all weight_norms in ONE dispatch --------------------------
__global__ __launch_bounds__(256) void wnorm_all(
    const float* __restrict__ c1v, const float* __restrict__ c1g, float* __restrict__ w1T,
    const float* __restrict__ c2v, const float* __restrict__ c2g, float* __restrict__ w2T,
    const float* __restrict__ c3v, const float* __restrict__ c3g, float* __restrict__ w3T,
    const float* __restrict__ d1v, const float* __restrict__ d1g, float* __restrict__ wd1,
    const float* __restrict__ d2v, const float* __restrict__ d2g, float* __restrict__ wd2P) {
    __shared__ float red[256];
    const int bid = blockIdx.x;
    const float *v, *g; float* w; int o, K, LD; bool tr;
    if (bid < 8)         { v = c1v; g = c1g; w = w1T;  o = bid;        K = 50;   LD = 8;  tr = true;  }
    else if (bid < 40)   { v = c2v; g = c2g; w = w2T;  o = bid - 8;    K = 200;  LD = 32; tr = true;  }
    else if (bid < 104)  { v = c3v; g = c3g; w = w3T;  o = bid - 40;   K = 800;  LD = 64; tr = true;  }
    else if (bid < 2160) { v = d1v; g = d1g; w = wd1;  o = bid - 104;  K = 256;  LD = 0;  tr = false; }
    else                 { v = d2v; g = d2g; w = wd2P; o = bid - 2160; K = 2056; LD = 12; tr = true;  }

    float s = 0.f;
    for (int k = threadIdx.x; k < K; k += 256) {
        float x = v[(size_t)o * K + k];
        s += x * x;
    }
    red[threadIdx.x] = s;
    __syncthreads();
    for (int off = 128; off > 0; off >>= 1) {
        if (threadIdx.x < off) red[threadIdx.x] += red[threadIdx.x + off];
        __syncthreads();
    }
    const float scale = g[o] / sqrtf(red[0]);
    for (int k = threadIdx.x; k < K; k += 256) {
        float val = scale * v[(size_t)o * K + k];
        if (tr) w[(size_t)k * LD + o] = val;
        else    w[(size_t)o * K + k] = val;
    }
}

// ---------------- pack x (0/1 floats) into per-pixel time bitmasks ----------
// wave = one pixel: coalesced 256B load, ballot, 8B store. x==1.0 -> bit set.
__global__ __launch_bounds__(256) void pack_x(const float* __restrict__ x,
                                              u64* __restrict__ xb) {
    const int wid = threadIdx.x >> 6, t = threadIdx.x & 63;
    const size_t p = (size_t)blockIdx.x * 4 + wid;  // 0..524287
    const float v = x[p * TT + t];
    const u64 m = __ballot(v > 0.5f);
    if (t == 0) xb[p] = m;
}

// ---------------- conv1 (2->8) on bitmasks, fused CUBA, bitmask out ---------
// Per tap: one wave-uniform u64 load (scalar pipe) + bit extract; FMA chain
// order (ci->ky->kx, per-acc) identical to the float version -> bit-identical.
__global__ __launch_bounds__(256) void conv1_cuba(const u64* __restrict__ xb,
                                                  const float* __restrict__ w1T,
                                                  u64* __restrict__ s1b) {
    __shared__ float lds[4][8][68];
    const int wid = RFL(threadIdx.x >> 6), t = threadIdx.x & 63;
    const int task = RFL(blockIdx.x) * 4 + wid;  // 0..16383
    const int spi = task & 1023, b = task >> 10;
    const int oy = spi >> 5, ox = spi & 31;

    float a0=0,a1=0,a2=0,a3=0,a4=0,a5=0,a6=0,a7=0;
    const u64* xq = xb + (size_t)b * 2 * 16384;

    if (oy >= 1 && ox >= 1) {
        const u64* xi = xq + (size_t)(oy * 4 - 1) * 128 + (ox * 4 - 1);
        for (int ci = 0; ci < 2; ci++) {
            u64 m[25];
#pragma unroll
            for (int ky = 0; ky < 5; ky++)
#pragma unroll
                for (int kx = 0; kx < 5; kx++)
                    m[ky * 5 + kx] = xi[ci * 16384 + ky * 128 + kx];
#pragma unroll
            for (int k = 0; k < 25; k++) {
                const float xvk = bit2f(m[k], t);
                const float4* wp = (const float4*)(w1T + (ci * 25 + k) * 8);
                const float4 wA = wp[0], wB = wp[1];
                a0 = fmaf(wA.x, xvk, a0); a1 = fmaf(wA.y, xvk, a1);
                a2 = fmaf(wA.z, xvk, a2); a3 = fmaf(wA.w, xvk, a3);
                a4 = fmaf(wB.x, xvk, a4); a5 = fmaf(wB.y, xvk, a5);
                a6 = fmaf(wB.z, xvk, a6); a7 = fmaf(wB.w, xvk, a7);
            }
        }
    } else {
        for (int ci = 0; ci < 2; ci++) {
#pragma unroll
            for (int ky = 0; ky < 5; ky++) {
                const int iy = oy * 4 + ky - 1;
                if (iy < 0 || iy >= 128) continue;
#pragma unroll
                for (int kx = 0; kx < 5; kx++) {
                    const int ix = ox * 4 + kx - 1;
                    if (ix < 0 || ix >= 128) continue;
                    const float xvk = bit2f(xq[ci * 16384 + iy * 128 + ix], t);
                    const float4* wp = (const float4*)(w1T + (ci * 25 + ky * 5 + kx) * 8);
                    const float4 wA = wp[0], wB = wp[1];
                    a0 = fmaf(wA.x, xvk, a0); a1 = fmaf(wA.y, xvk, a1);
                    a2 = fmaf(wA.z, xvk, a2); a3 = fmaf(wA.w, xvk, a3);
                    a4 = fmaf(wB.x, xvk, a4); a5 = fmaf(wB.y, xvk, a5);
                    a6 = fmaf(wB.z, xvk, a6); a7 = fmaf(wB.w, xvk, a7);
                }
            }
        }
    }
    lds[wid][0][t] = a0; lds[wid][1][t] = a1; lds[wid][2][t] = a2; lds[wid][3][t] = a3;
    lds[wid][4][t] = a4; lds[wid][5][t] = a5; lds[wid][6][t] = a6; lds[wid][7][t] = a7;
    __syncthreads();
    if (t < 8) {  // scan channel t in-register, write spikes back to LDS
        float* row = &lds[wid][t][0];
        float c = 0.f, v = 0.f;
        for (int tc = 0; tc < 4; tc++) {
            float4 r0 = *(const float4*)&row[tc * 16 + 0];
            float4 r1 = *(const float4*)&row[tc * 16 + 4];
            float4 r2 = *(const float4*)&row[tc * 16 + 8];
            float4 r3 = *(const float4*)&row[tc * 16 + 12];
            scan4(c, v, r0); scan4(c, v, r1); scan4(c, v, r2); scan4(c, v, r3);
            *(float4*)&row[tc * 16 + 0] = r0; *(float4*)&row[tc * 16 + 4] = r1;
            *(float4*)&row[tc * 16 + 8] = r2; *(float4*)&row[tc * 16 + 12] = r3;
        }
    }
    __syncthreads();
    u64* ob = s1b + (size_t)b * 8 * 1024 + spi;
#pragma unroll
    for (int ch = 0; ch < 8; ch++) {
        const u64 m = __ballot(lds[wid][ch][t] > 0.5f);
        if (t == 0) ob[(size_t)ch * 1024] = m;
    }
}

// ---------------- conv2 (8->32) on bitmasks, fused CUBA, float out ----------
__global__ __launch_bounds__(256) void conv2_cuba(const u64* __restrict__ s1b,
                                                  const float* __restrict__ w2T,
                                                  float* __restrict__ s2) {
    __shared__ float lds[4][16][68];
    const int wid = RFL(threadIdx.x >> 6), t = threadIdx.x & 63;
    const int task = RFL(blockIdx.x) * 4 + wid;  // 0..2047
    const int og = task & 1;
    const int spi = (task >> 1) & 63;
    const int b = task >> 7;
    const int oy = spi >> 3, ox = spi & 7;

    float a[16];
#pragma unroll
    for (int j = 0; j < 16; j++) a[j] = 0.f;
    const u64* sb = s1b + (size_t)b * 8 * 1024;

    if (oy >= 1 && ox >= 1) {
        const u64* si = sb + (size_t)(oy * 4 - 1) * 32 + (ox * 4 - 1);
        for (int ci = 0; ci < 8; ci++) {
            u64 m[25];
#pragma unroll
            for (int ky = 0; ky < 5; ky++)
#pragma unroll
                for (int kx = 0; kx < 5; kx++)
                    m[ky * 5 + kx] = si[ci * 1024 + ky * 32 + kx];
#pragma unroll
            for (int k = 0; k < 25; k++) {
                const float xvk = bit2f(m[k], t);
                const float4* wp = (const float4*)(w2T + (ci * 25 + k) * 32 + og * 16);
                const float4 w0 = wp[0], w1 = wp[1], w2 = wp[2], w3 = wp[3];
                a[0]  = fmaf(w0.x, xvk, a[0]);  a[1]  = fmaf(w0.y, xvk, a[1]);
                a[2]  = fmaf(w0.z, xvk, a[2]);  a[3]  = fmaf(w0.w, xvk, a[3]);
                a[4]  = fmaf(w1.x, xvk, a[4]);  a[5]  = fmaf(w1.y, xvk, a[5]);
                a[6]  = fmaf(w1.z, xvk, a[6]);  a[7]  = fmaf(w1.w, xvk, a[7]);
                a[8]  = fmaf(w2.x, xvk, a[8]);  a[9]  = fmaf(w2.y, xvk, a[9]);
                a[10] = fmaf(w2.z, xvk, a[10]); a[11] = fmaf(w2.w, xvk, a[11]);
                a[12] = fmaf(w3.x, xvk, a[12]); a[13] = fmaf(w3.y, xvk, a[13]);
                a[14] = fmaf(w3.z, xvk, a[14]); a[15] = fmaf(w3.w, xvk, a[15]);
            }
        }
    } else {
        for (int ci = 0; ci < 8; ci++) {
#pragma unroll
            for (int ky = 0; ky < 5; ky++) {
                const int iy = oy * 4 + ky - 1;
                if (iy < 0 || iy >= 32) continue;
#pragma unroll
                for (int kx = 0; kx < 5; kx++) {
                    const int ix = ox * 4 + kx - 1;
                    if (ix < 0 || ix >= 32) continue;
                    const float xvk = bit2f(sb[ci * 1024 + iy * 32 + ix], t);
                    const float4* wp =
                        (const float4*)(w2T + (ci * 25 + ky * 5 + kx) * 32 + og * 16);
                    const float4 w0 = wp[0], w1 = wp[1], w2 = wp[2], w3 = wp[3];
                    a[0]  = fmaf(w0.x, xvk, a[0]);  a[1]  = fmaf(w0.y, xvk, a[1]);
                    a[2]  = fmaf(w0.z, xvk, a[2]);  a[3]  = fmaf(w0.w, xvk, a[3]);
                    a[4]  = fmaf(w1.x, xvk, a[4]);  a[5]  = fmaf(w1.y, xvk, a[5]);
                    a[6]  = fmaf(w1.z, xvk, a[6]);  a[7]  = fmaf(w1.w, xvk, a[7]);
                    a[8]  = fmaf(w2.x, xvk, a[8]);  a[9]  = fmaf(w2.y, xvk, a[9]);
                    a[10] = fmaf(w2.z, xvk, a[10]); a[11] = fmaf(w2.w, xvk, a[11]);
                    a[12] = fmaf(w3.x, xvk, a[12]); a[13] = fmaf(w3.y, xvk, a[13]);
                    a[14] = fmaf(w3.z, xvk, a[14]); a[15] = fmaf(w3.w, xvk, a[15]);
                }
            }
        }
    }
#pragma unroll
    for (int j = 0; j < 16; j++) lds[wid][j][t] = a[j];
    __syncthreads();
    if (t < 16) {
        const float* row = &lds[wid][t][0];
        float4* op = (float4*)(s2 + (((size_t)b * 32 + og * 16 + t) * 64 + spi) * TT);
        float c = 0.f, v = 0.f;
        for (int tc = 0; tc < 4; tc++) {
            float4 r0 = *(const float4*)&row[tc * 16 + 0];
            float4 r1 = *(const float4*)&row[tc * 16 + 4];
            float4 r2 = *(const float4*)&row[tc * 16 + 8];
            float4 r3 = *(const float4*)&row[tc * 16 + 12];
            scan4(c, v, r0); scan4(c, v, r1); scan4(c, v, r2); scan4(c, v, r3);
            op[tc * 4 + 0] = r0; op[tc * 4 + 1] = r1;
            op[tc * 4 + 2] = r2; op[tc * 4 + 3] = r3;
        }
    }
}

// ---------------- conv3 (32->64) fused with CUBA ----------------------------
template <int OY, int OX>
__device__ __forceinline__ void conv3_acc(const float* __restrict__ xb,
                                          const float* __restrict__ wTo,
                                          int wid, float* __restrict__ acc) {
    constexpr int KY0 = (OY == 0) ? 1 : 0;
    constexpr int KX0 = (OX == 0) ? 1 : 0;
    constexpr int NKY = 5 - KY0;
    constexpr int NKX = 5 - KX0;
    for (int c8 = 0; c8 < 8; c8++) {
        const int ci = wid * 8 + c8;
        float xv[NKY * NKX];
#pragma unroll
        for (int ky = KY0; ky < 5; ky++) {
#pragma unroll
            for (int kx = KX0; kx < 5; kx++) {
                const int iy = OY * 4 + ky - 1;
                const int ix = OX * 4 + kx - 1;
                xv[(ky - KY0) * NKX + (kx - KX0)] =
                    xb[((size_t)((ci * 8 + iy) * 8 + ix)) * TT];
            }
        }
#pragma unroll
        for (int ky = KY0; ky < 5; ky++) {
#pragma unroll
            for (int kx = KX0; kx < 5; kx++) {
                const float xvk = xv[(ky - KY0) * NKX + (kx - KX0)];
                const float4* wp = (const float4*)(wTo + (ci * 25 + ky * 5 + kx) * 64);
                const float4 wA = wp[0], wB = wp[1];
                acc[0] = fmaf(wA.x, xvk, acc[0]); acc[1] = fmaf(wA.y, xvk, acc[1]);
                acc[2] = fmaf(wA.z, xvk, acc[2]); acc[3] = fmaf(wA.w, xvk, acc[3]);
                acc[4] = fmaf(wB.x, xvk, acc[4]); acc[5] = fmaf(wB.y, xvk, acc[5]);
                acc[6] = fmaf(wB.z, xvk, acc[6]); acc[7] = fmaf(wB.w, xvk, acc[7]);
            }
        }
    }
}

__global__ __launch_bounds__(256) void conv3_cuba(const float* __restrict__ s2,
                                                  const float* __restrict__ wT,
                                                  float* __restrict__ s3) {
    __shared__ float red[4][8][68];
    const int wid = RFL(threadIdx.x >> 6), t = threadIdx.x & 63;
    const int og = RFL(blockIdx.x) & 7;
    const int spi = (RFL(blockIdx.x) >> 3) & 3;
    const int b = RFL(blockIdx.x) >> 5;

    float acc[8];
#pragma unroll
    for (int j = 0; j < 8; j++) acc[j] = 0.f;
    const float* xb = s2 + (size_t)b * 32 * 8 * 8 * TT + t;
    const float* wTo = wT + og * 8;

    switch (spi) {
        case 0: conv3_acc<0, 0>(xb, wTo, wid, acc); break;
        case 1: conv3_acc<0, 1>(xb, wTo, wid, acc); break;
        case 2: conv3_acc<1, 0>(xb, wTo, wid, acc); break;
        default: conv3_acc<1, 1>(xb, wTo, wid, acc); break;
    }
#pragma unroll
    for (int j = 0; j < 8; j++) red[wid][j][t] = acc[j];
    __syncthreads();
    if (wid == 0) {
#pragma unroll
        for (int j = 0; j < 8; j++)
            red[0][j][t] = ((red[0][j][t] + red[1][j][t]) + red[2][j][t]) + red[3][j][t];
    }
    __syncthreads();
    if (threadIdx.x < 8) {
        const int j = threadIdx.x;
        const float* row = &red[0][j][0];
        float4* op = (float4*)(s3 + ((size_t)b * 256 + og * 32 + j * 4 + spi) * TT);
        float c = 0.f, v = 0.f;
        for (int tc = 0; tc < 4; tc++) {
            float4 r0 = *(const float4*)&row[tc * 16 + 0];
            float4 r1 = *(const float4*)&row[tc * 16 + 4];
            float4 r2 = *(const float4*)&row[tc * 16 + 8];
            float4 r3 = *(const float4*)&row[tc * 16 + 12];
            scan4(c, v, r0); scan4(c, v, r1); scan4(c, v, r2); scan4(c, v, r3);
            op[tc * 4 + 0] = r0; op[tc * 4 + 1] = r1;
            op[tc * 4 + 2] = r2; op[tc * 4 + 3] = r3;
        }
    }
}

// ---------------- dense1 (256 -> 2056) fused with CUBA ----------------------
__global__ __launch_bounds__(256) void dense1_cuba(const float* __restrict__ s3,
                                                   const float* __restrict__ w,
                                                   float* __restrict__ s4) {
    __shared__ float lds[4][8][68];
    const int wid = threadIdx.x >> 6, t = threadIdx.x & 63;
    const int task = blockIdx.x * 4 + wid;  // 0..4111  (16 b x 257 og)
    const int bq = task / 257;
    const int ogq = task - bq * 257;
    const int b = RFL(bq);
    const int o0 = RFL(ogq * 8);

    float a0=0,a1=0,a2=0,a3=0,a4=0,a5=0,a6=0,a7=0;
    const float* ab = s3 + (size_t)b * 256 * TT + t;
    const float* r0 = w + (size_t)(o0 + 0) * 256;
    const float* r1 = w + (size_t)(o0 + 1) * 256;
    const float* r2 = w + (size_t)(o0 + 2) * 256;
    const float* r3 = w + (size_t)(o0 + 3) * 256;
    const float* r4 = w + (size_t)(o0 + 4) * 256;
    const float* r5 = w + (size_t)(o0 + 5) * 256;
    const float* r6 = w + (size_t)(o0 + 6) * 256;
    const float* r7 = w + (size_t)(o0 + 7) * 256;

#pragma unroll 2
    for (int i = 0; i < 256; i += 4) {
        const float av0 = ab[(size_t)(i + 0) * TT];
        const float av1 = ab[(size_t)(i + 1) * TT];
        const float av2 = ab[(size_t)(i + 2) * TT];
        const float av3 = ab[(size_t)(i + 3) * TT];
        const float4 q0 = *(const float4*)(r0 + i);
        const float4 q1 = *(const float4*)(r1 + i);
        const float4 q2 = *(const float4*)(r2 + i);
        const float4 q3 = *(const float4*)(r3 + i);
        const float4 q4 = *(const float4*)(r4 + i);
        const float4 q5 = *(const float4*)(r5 + i);
        const float4 q6 = *(const float4*)(r6 + i);
        const float4 q7 = *(const float4*)(r7 + i);
        a0 = fmaf(q0.x, av0, a0); a1 = fmaf(q1.x, av0, a1);
        a2 = fmaf(q2.x, av0, a2); a3 = fmaf(q3.x, av0, a3);
        a4 = fmaf(q4.x, av0, a4); a5 = fmaf(q5.x, av0, a5);
        a6 = fmaf(q6.x, av0, a6); a7 = fmaf(q7.x, av0, a7);
        a0 = fmaf(q0.y, av1, a0); a1 = fmaf(q1.y, av1, a1);
        a2 = fmaf(q2.y, av1, a2); a3 = fmaf(q3.y, av1, a3);
        a4 = fmaf(q4.y, av1, a4); a5 = fmaf(q5.y, av1, a5);
        a6 = fmaf(q6.y, av1, a6); a7 = fmaf(q7.y, av1, a7);
        a0 = fmaf(q0.z, av2, a0); a1 = fmaf(q1.z, av2, a1);
        a2 = fmaf(q2.z, av2, a2); a3 = fmaf(q3.z, av2, a3);
        a4 = fmaf(q4.z, av2, a4); a5 = fmaf(q5.z, av2, a5);
        a6 = fmaf(q6.z, av2, a6); a7 = fmaf(q7.z, av2, a7);
        a0 = fmaf(q0.w, av3, a0); a1 = fmaf(q1.w, av3, a1);
        a2 = fmaf(q2.w, av3, a2); a3 = fmaf(q3.w, av3, a3);
        a4 = fmaf(q4.w, av3, a4); a5 = fmaf(q5.w, av3, a5);
        a6 = fmaf(q6.w, av3, a6); a7 = fmaf(q7.w, av3, a7);
    }
    lds[wid][0][t] = a0; lds[wid][1][t] = a1; lds[wid][2][t] = a2; lds[wid][3][t] = a3;
    lds[wid][4][t] = a4; lds[wid][5][t] = a5; lds[wid][6][t] = a6; lds[wid][7][t] = a7;
    __syncthreads();
    if (t < 8) {
        const float* row = &lds[wid][t][0];
        float4* op = (float4*)(s4 + ((size_t)b * 2056 + o0 + t) * TT);
        float c = 0.f, v = 0.f;
        for (int tc = 0; tc < 4; tc++) {
            float4 r0q = *(const float4*)&row[tc * 16 + 0];
            float4 r1q = *(const float4*)&row[tc * 16 + 4];
            float4 r2q = *(const float4*)&row[tc * 16 + 8];
            float4 r3q = *(const float4*)&row[tc * 16 + 12];
            scan4(c, v, r0q); scan4(c, v, r1q); scan4(c, v, r2q); scan4(c, v, r3q);
            op[tc * 4 + 0] = r0q; op[tc * 4 + 1] = r1q;
            op[tc * 4 + 2] = r2q; op[tc * 4 + 3] = r3q;
        }
    }
}

// ---------------- dense2 stage 1: split-K partial sums ----------------------
__global__ __launch_bounds__(256) void dense2_part(const float* __restrict__ s4,
                                                   const float* __restrict__ wP,
                                                   float* __restrict__ z4p) {
    __shared__ float red[4][11][64];
    const int sp = blockIdx.x, b = blockIdx.y;
    const int w = threadIdx.x >> 6, t = threadIdx.x & 63;
    const int i0 = sp * 257, iend = i0 + 257;  // 2056 = 8*257
    const float* src = s4 + (size_t)b * 2056 * TT + t;

    float acc[11];
#pragma unroll
    for (int j = 0; j < 11; j++) acc[j] = 0.f;

    for (int i = i0 + w; i < iend; i += 4) {
        const float xv = src[(size_t)i * TT];
        const float4* wp = (const float4*)(wP + (size_t)i * 12);
        const float4 w0 = wp[0], w1 = wp[1], w2 = wp[2];
        acc[0]  = fmaf(w0.x, xv, acc[0]);  acc[1]  = fmaf(w0.y, xv, acc[1]);
        acc[2]  = fmaf(w0.z, xv, acc[2]);  acc[3]  = fmaf(w0.w, xv, acc[3]);
        acc[4]  = fmaf(w1.x, xv, acc[4]);  acc[5]  = fmaf(w1.y, xv, acc[5]);
        acc[6]  = fmaf(w1.z, xv, acc[6]);  acc[7]  = fmaf(w1.w, xv, acc[7]);
        acc[8]  = fmaf(w2.x, xv, acc[8]);  acc[9]  = fmaf(w2.y, xv, acc[9]);
        acc[10] = fmaf(w2.z, xv, acc[10]);
    }
#pragma unroll
    for (int j = 0; j < 11; j++) red[w][j][t] = acc[j];
    __syncthreads();
    if (w == 0) {
#pragma unroll
        for (int j = 0; j < 11; j++) {
            const float s = red[0][j][t] + red[1][j][t] + red[2][j][t] + red[3][j][t];
            z4p[(((size_t)b * 8 + sp) * 11 + j) * TT + t] = s;
        }
    }
}

// ---------------- dense2 stage 2: fixed-order reduce + final CUBA scan ------
__global__ __launch_bounds__(256) void dense2_scan(const float* __restrict__ z4p,
                                                   float* __restrict__ out) {
    __shared__ float z[11][64];
    const int b = blockIdx.x;
    for (int idx = threadIdx.x; idx < 11 * 64; idx += 256) {
        const int o = idx >> 6, t = idx & 63;
        float s = 0.f;
#pragma unroll
        for (int sp = 0; sp < 8; sp++)
            s += z4p[(((size_t)b * 8 + sp) * 11 + o) * TT + t];
        z[o][t] = s;
    }
    __syncthreads();
    if (threadIdx.x < 11) {
        const int o = threadIdx.x;
        float c = 0.f, v = 0.f;
        float* op = out + ((size_t)b * 11 + o) * TT;
#pragma unroll
        for (int t = 0; t < TT; t++) {
            float zz = z[o][t];
            scanc(c, v, zz);
            op[t] = zz;
        }
    }
}

extern "C" void kernel_launch(void* const* d_in, const int* in_sizes, int n_in,
                              void* d_out, int out_size, void* d_ws, size_t ws_size,
                              hipStream_t stream) {
    const float* x   = (const float*)d_in[0];
    const float* c1v = (const float*)d_in[1];  const float* c1g = (const float*)d_in[2];
    const float* c2v = (const float*)d_in[3];  const float* c2g = (const float*)d_in[4];
    const float* c3v = (const float*)d_in[5];  const float* c3g = (const float*)d_in[6];
    const float* d1v = (const float*)d_in[7];  const float* d1g = (const float*)d_in[8];
    const float* d2v = (const float*)d_in[9];  const float* d2g = (const float*)d_in[10];

    float* ws = (float*)d_ws;
    // weight region
    float* w1T  = ws + 0;        // (50,8)     = 400
    float* w2T  = ws + 400;      // (200,32)   = 6400
    float* w3T  = ws + 6800;     // (800,64)   = 51200
    float* wd1  = ws + 58000;    // (2056,256) original layout = 526336
    float* wd2P = ws + 584336;   // (2056,12) padded = 24672
    // activation regions
    float* A = ws + 609008;
    float* B = A + 8388608;
    float* s3  = A;              // dense-in spikes (b,256,t)
    float* s4  = A + 262144;     // dense1 spikes (b,2056,t)
    float* s2  = B;              // conv2 spikes (b,32,8,8,t)
    float* z4p = B + 2097152;    // dense2 partials (b,8,11,t)
    // bitmask regions (8B-aligned: float offsets are even)
    u64* xbits  = (u64*)(ws + 13191920);  // 524288 u64 = 4 MB
    u64* s1bits = (u64*)(ws + 14240496);  // 131072 u64 = 1 MB
    (void)ws_size; (void)in_sizes; (void)n_in; (void)out_size;

    wnorm_all<<<dim3(2171), dim3(256), 0, stream>>>(c1v, c1g, w1T, c2v, c2g, w2T,
                                                    c3v, c3g, w3T, d1v, d1g, wd1,
                                                    d2v, d2g, wd2P);
    pack_x<<<dim3(131072), dim3(256), 0, stream>>>(x, xbits);

    conv1_cuba <<<dim3(4096), dim3(256), 0, stream>>>(xbits, w1T, s1bits);
    conv2_cuba <<<dim3(512),  dim3(256), 0, stream>>>(s1bits, w2T, s2);
    conv3_cuba <<<dim3(512),  dim3(256), 0, stream>>>(s2, w3T, s3);
    dense1_cuba<<<dim3(1028), dim3(256), 0, stream>>>(s3, wd1, s4);
    dense2_part<<<dim3(8, 16), dim3(256), 0, stream>>>(s4, wd2P, z4p);
    dense2_scan<<<dim3(16),   dim3(256), 0, stream>>>(z4p, (float*)d_out);
}

// Round 11
// 170.561 us; speedup vs baseline: 1.1552x; 1.1552x over previous
//
#include <hip/hip_runtime.h>
#include <cstddef>

#define TT 64  // timesteps

#define RFL(x) __builtin_amdgcn_readfirstlane(x)

typedef unsigned long long u64;

// ---------------- CUBA LIF step helpers ----------------
__device__ __forceinline__ void scanc(float& c, float& v, float& z) {
    c = fmaf(0.7f, c, z);
    v = fmaf(0.75f, v, c);
    float s = (v >= 1.0f) ? 1.0f : 0.0f;
    v = (v >= 1.0f) ? 0.0f : v;
    z = s;
}
__device__ __forceinline__ void scan4(float& c, float& v, float4& a) {
    scanc(c, v, a.x); scanc(c, v, a.y); scanc(c, v, a.z); scanc(c, v, a.w);
}
__device__ __forceinline__ float bit2f(u64 m, int t) {
    return (float)((m >> t) & 1ULL);  // exactly 0.0f or 1.0f
}

// ---------------- all weight_norms in ONE dispatch --------------------------
__global__ __launch_bounds__(256) void wnorm_all(
    const float* __restrict__ c1v, const float* __restrict__ c1g, float* __restrict__ w1T,
    const float* __restrict__ c2v, const float* __restrict__ c2g, float* __restrict__ w2T,
    const float* __restrict__ c3v, const float* __restrict__ c3g, float* __restrict__ w3T,
    const float* __restrict__ d1v, const float* __restrict__ d1g, float* __restrict__ wd1,
    const float* __restrict__ d2v, const float* __restrict__ d2g, float* __restrict__ wd2P) {
    __shared__ float red[256];
    const int bid = blockIdx.x;
    const float *v, *g; float* w; int o, K, LD; bool tr;
    if (bid < 8)         { v = c1v; g = c1g; w = w1T;  o = bid;        K = 50;   LD = 8;  tr = true;  }
    else if (bid < 40)   { v = c2v; g = c2g; w = w2T;  o = bid - 8;    K = 200;  LD = 32; tr = true;  }
    else if (bid < 104)  { v = c3v; g = c3g; w = w3T;  o = bid - 40;   K = 800;  LD = 64; tr = true;  }
    else if (bid < 2160) { v = d1v; g = d1g; w = wd1;  o = bid - 104;  K = 256;  LD = 0;  tr = false; }
    else                 { v = d2v; g = d2g; w = wd2P; o = bid - 2160; K = 2056; LD = 12; tr = true;  }

    float s = 0.f;
    for (int k = threadIdx.x; k < K; k += 256) {
        float x = v[(size_t)o * K + k];
        s += x * x;
    }
    red[threadIdx.x] = s;
    __syncthreads();
    for (int off = 128; off > 0; off >>= 1) {
        if (threadIdx.x < off) red[threadIdx.x] += red[threadIdx.x + off];
        __syncthreads();
    }
    const float scale = g[o] / sqrtf(red[0]);
    for (int k = threadIdx.x; k < K; k += 256) {
        float val = scale * v[(size_t)o * K + k];
        if (tr) w[(size_t)k * LD + o] = val;
        else    w[(size_t)o * K + k] = val;
    }
}

// ---------------- pack x (0/1 floats) into per-pixel time bitmasks ----------
// 16-lane group = one pixel; lane loads float4 (16 B) covering t = sub*4..+3;
// nibble -> shifted u64 -> OR-reduce via shfl_xor within the group. Bit t of
// the result == (x[t] > 0.5), identical layout to the previous ballot version.
__global__ __launch_bounds__(256) void pack_x(const float* __restrict__ x,
                                              u64* __restrict__ xb) {
    const int sub = threadIdx.x & 15;
    const int grp = threadIdx.x >> 4;  // 0..15 pixel-slot within block
    for (size_t base = (size_t)blockIdx.x * 16; base < 524288;
         base += (size_t)gridDim.x * 16) {
        const size_t p = base + grp;
        const float4 v = *(const float4*)(x + p * TT + sub * 4);
        const unsigned int nib = (v.x > 0.5f ? 1u : 0u) | (v.y > 0.5f ? 2u : 0u) |
                                 (v.z > 0.5f ? 4u : 0u) | (v.w > 0.5f ? 8u : 0u);
        u64 word = (u64)nib << (4 * sub);
        word |= __shfl_xor(word, 1);
        word |= __shfl_xor(word, 2);
        word |= __shfl_xor(word, 4);
        word |= __shfl_xor(word, 8);
        if (sub == 0) xb[p] = word;
    }
}

// ---------------- conv1 (2->8) on bitmasks, fused CUBA, bitmask out ---------
__global__ __launch_bounds__(256) void conv1_cuba(const u64* __restrict__ xb,
                                                  const float* __restrict__ w1T,
                                                  u64* __restrict__ s1b) {
    __shared__ float lds[4][8][68];
    const int wid = RFL(threadIdx.x >> 6), t = threadIdx.x & 63;
    const int task = RFL(blockIdx.x) * 4 + wid;  // 0..16383
    const int spi = task & 1023, b = task >> 10;
    const int oy = spi >> 5, ox = spi & 31;

    float a0=0,a1=0,a2=0,a3=0,a4=0,a5=0,a6=0,a7=0;
    const u64* xq = xb + (size_t)b * 2 * 16384;

    if (oy >= 1 && ox >= 1) {
        const u64* xi = xq + (size_t)(oy * 4 - 1) * 128 + (ox * 4 - 1);
        for (int ci = 0; ci < 2; ci++) {
            u64 m[25];
#pragma unroll
            for (int ky = 0; ky < 5; ky++)
#pragma unroll
                for (int kx = 0; kx < 5; kx++)
                    m[ky * 5 + kx] = xi[ci * 16384 + ky * 128 + kx];
#pragma unroll
            for (int k = 0; k < 25; k++) {
                const float xvk = bit2f(m[k], t);
                const float4* wp = (const float4*)(w1T + (ci * 25 + k) * 8);
                const float4 wA = wp[0], wB = wp[1];
                a0 = fmaf(wA.x, xvk, a0); a1 = fmaf(wA.y, xvk, a1);
                a2 = fmaf(wA.z, xvk, a2); a3 = fmaf(wA.w, xvk, a3);
                a4 = fmaf(wB.x, xvk, a4); a5 = fmaf(wB.y, xvk, a5);
                a6 = fmaf(wB.z, xvk, a6); a7 = fmaf(wB.w, xvk, a7);
            }
        }
    } else {
        for (int ci = 0; ci < 2; ci++) {
#pragma unroll
            for (int ky = 0; ky < 5; ky++) {
                const int iy = oy * 4 + ky - 1;
                if (iy < 0 || iy >= 128) continue;
#pragma unroll
                for (int kx = 0; kx < 5; kx++) {
                    const int ix = ox * 4 + kx - 1;
                    if (ix < 0 || ix >= 128) continue;
                    const float xvk = bit2f(xq[ci * 16384 + iy * 128 + ix], t);
                    const float4* wp = (const float4*)(w1T + (ci * 25 + ky * 5 + kx) * 8);
                    const float4 wA = wp[0], wB = wp[1];
                    a0 = fmaf(wA.x, xvk, a0); a1 = fmaf(wA.y, xvk, a1);
                    a2 = fmaf(wA.z, xvk, a2); a3 = fmaf(wA.w, xvk, a3);
                    a4 = fmaf(wB.x, xvk, a4); a5 = fmaf(wB.y, xvk, a5);
                    a6 = fmaf(wB.z, xvk, a6); a7 = fmaf(wB.w, xvk, a7);
                }
            }
        }
    }
    lds[wid][0][t] = a0; lds[wid][1][t] = a1; lds[wid][2][t] = a2; lds[wid][3][t] = a3;
    lds[wid][4][t] = a4; lds[wid][5][t] = a5; lds[wid][6][t] = a6; lds[wid][7][t] = a7;
    __syncthreads();
    if (t < 8) {  // scan channel t in-register, write spikes back to LDS
        float* row = &lds[wid][t][0];
        float c = 0.f, v = 0.f;
        for (int tc = 0; tc < 4; tc++) {
            float4 r0 = *(const float4*)&row[tc * 16 + 0];
            float4 r1 = *(const float4*)&row[tc * 16 + 4];
            float4 r2 = *(const float4*)&row[tc * 16 + 8];
            float4 r3 = *(const float4*)&row[tc * 16 + 12];
            scan4(c, v, r0); scan4(c, v, r1); scan4(c, v, r2); scan4(c, v, r3);
            *(float4*)&row[tc * 16 + 0] = r0; *(float4*)&row[tc * 16 + 4] = r1;
            *(float4*)&row[tc * 16 + 8] = r2; *(float4*)&row[tc * 16 + 12] = r3;
        }
    }
    __syncthreads();
    u64* ob = s1b + (size_t)b * 8 * 1024 + spi;
#pragma unroll
    for (int ch = 0; ch < 8; ch++) {
        const u64 m = __ballot(lds[wid][ch][t] > 0.5f);
        if (t == 0) ob[(size_t)ch * 1024] = m;
    }
}

// ---------------- conv2 (8->32) on bitmasks, fused CUBA, float out ----------
__global__ __launch_bounds__(256) void conv2_cuba(const u64* __restrict__ s1b,
                                                  const float* __restrict__ w2T,
                                                  float* __restrict__ s2) {
    __shared__ float lds[4][16][68];
    const int wid = RFL(threadIdx.x >> 6), t = threadIdx.x & 63;
    const int task = RFL(blockIdx.x) * 4 + wid;  // 0..2047
    const int og = task & 1;
    const int spi = (task >> 1) & 63;
    const int b = task >> 7;
    const int oy = spi >> 3, ox = spi & 7;

    float a[16];
#pragma unroll
    for (int j = 0; j < 16; j++) a[j] = 0.f;
    const u64* sb = s1b + (size_t)b * 8 * 1024;

    if (oy >= 1 && ox >= 1) {
        const u64* si = sb + (size_t)(oy * 4 - 1) * 32 + (ox * 4 - 1);
        for (int ci = 0; ci < 8; ci++) {
            u64 m[25];
#pragma unroll
            for (int ky = 0; ky < 5; ky++)
#pragma unroll
                for (int kx = 0; kx < 5; kx++)
                    m[ky * 5 + kx] = si[ci * 1024 + ky * 32 + kx];
#pragma unroll
            for (int k = 0; k < 25; k++) {
                const float xvk = bit2f(m[k], t);
                const float4* wp = (const float4*)(w2T + (ci * 25 + k) * 32 + og * 16);
                const float4 w0 = wp[0], w1 = wp[1], w2 = wp[2], w3 = wp[3];
                a[0]  = fmaf(w0.x, xvk, a[0]);  a[1]  = fmaf(w0.y, xvk, a[1]);
                a[2]  = fmaf(w0.z, xvk, a[2]);  a[3]  = fmaf(w0.w, xvk, a[3]);
                a[4]  = fmaf(w1.x, xvk, a[4]);  a[5]  = fmaf(w1.y, xvk, a[5]);
                a[6]  = fmaf(w1.z, xvk, a[6]);  a[7]  = fmaf(w1.w, xvk, a[7]);
                a[8]  = fmaf(w2.x, xvk, a[8]);  a[9]  = fmaf(w2.y, xvk, a[9]);
                a[10] = fmaf(w2.z, xvk, a[10]); a[11] = fmaf(w2.w, xvk, a[11]);
                a[12] = fmaf(w3.x, xvk, a[12]); a[13] = fmaf(w3.y, xvk, a[13]);
                a[14] = fmaf(w3.z, xvk, a[14]); a[15] = fmaf(w3.w, xvk, a[15]);
            }
        }
    } else {
        for (int ci = 0; ci < 8; ci++) {
#pragma unroll
            for (int ky = 0; ky < 5; ky++) {
                const int iy = oy * 4 + ky - 1;
                if (iy < 0 || iy >= 32) continue;
#pragma unroll
                for (int kx = 0; kx < 5; kx++) {
                    const int ix = ox * 4 + kx - 1;
                    if (ix < 0 || ix >= 32) continue;
                    const float xvk = bit2f(sb[ci * 1024 + iy * 32 + ix], t);
                    const float4* wp =
                        (const float4*)(w2T + (ci * 25 + ky * 5 + kx) * 32 + og * 16);
                    const float4 w0 = wp[0], w1 = wp[1], w2 = wp[2], w3 = wp[3];
                    a[0]  = fmaf(w0.x, xvk, a[0]);  a[1]  = fmaf(w0.y, xvk, a[1]);
                    a[2]  = fmaf(w0.z, xvk, a[2]);  a[3]  = fmaf(w0.w, xvk, a[3]);
                    a[4]  = fmaf(w1.x, xvk, a[4]);  a[5]  = fmaf(w1.y, xvk, a[5]);
                    a[6]  = fmaf(w1.z, xvk, a[6]);  a[7]  = fmaf(w1.w, xvk, a[7]);
                    a[8]  = fmaf(w2.x, xvk, a[8]);  a[9]  = fmaf(w2.y, xvk, a[9]);
                    a[10] = fmaf(w2.z, xvk, a[10]); a[11] = fmaf(w2.w, xvk, a[11]);
                    a[12] = fmaf(w3.x, xvk, a[12]); a[13] = fmaf(w3.y, xvk, a[13]);
                    a[14] = fmaf(w3.z, xvk, a[14]); a[15] = fmaf(w3.w, xvk, a[15]);
                }
            }
        }
    }
#pragma unroll
    for (int j = 0; j < 16; j++) lds[wid][j][t] = a[j];
    __syncthreads();
    if (t < 16) {
        const float* row = &lds[wid][t][0];
        float4* op = (float4*)(s2 + (((size_t)b * 32 + og * 16 + t) * 64 + spi) * TT);
        float c = 0.f, v = 0.f;
        for (int tc = 0; tc < 4; tc++) {
            float4 r0 = *(const float4*)&row[tc * 16 + 0];
            float4 r1 = *(const float4*)&row[tc * 16 + 4];
            float4 r2 = *(const float4*)&row[tc * 16 + 8];
            float4 r3 = *(const float4*)&row[tc * 16 + 12];
            scan4(c, v, r0); scan4(c, v, r1); scan4(c, v, r2); scan4(c, v, r3);
            op[tc * 4 + 0] = r0; op[tc * 4 + 1] = r1;
            op[tc * 4 + 2] = r2; op[tc * 4 + 3] = r3;
        }
    }
}

// ---------------- conv3 (32->64) fused with CUBA ----------------------------
template <int OY, int OX>
__device__ __forceinline__ void conv3_acc(const float* __restrict__ xb,
                                          const float* __restrict__ wTo,
                                          int wid, float* __restrict__ acc) {
    constexpr int KY0 = (OY == 0) ? 1 : 0;
    constexpr int KX0 = (OX == 0) ? 1 : 0;
    constexpr int NKY = 5 - KY0;
    constexpr int NKX = 5 - KX0;
    for (int c8 = 0; c8 < 8; c8++) {
        const int ci = wid * 8 + c8;
        float xv[NKY * NKX];
#pragma unroll
        for (int ky = KY0; ky < 5; ky++) {
#pragma unroll
            for (int kx = KX0; kx < 5; kx++) {
                const int iy = OY * 4 + ky - 1;
                const int ix = OX * 4 + kx - 1;
                xv[(ky - KY0) * NKX + (kx - KX0)] =
                    xb[((size_t)((ci * 8 + iy) * 8 + ix)) * TT];
            }
        }
#pragma unroll
        for (int ky = KY0; ky < 5; ky++) {
#pragma unroll
            for (int kx = KX0; kx < 5; kx++) {
                const float xvk = xv[(ky - KY0) * NKX + (kx - KX0)];
                const float4* wp = (const float4*)(wTo + (ci * 25 + ky * 5 + kx) * 64);
                const float4 wA = wp[0], wB = wp[1];
                acc[0] = fmaf(wA.x, xvk, acc[0]); acc[1] = fmaf(wA.y, xvk, acc[1]);
                acc[2] = fmaf(wA.z, xvk, acc[2]); acc[3] = fmaf(wA.w, xvk, acc[3]);
                acc[4] = fmaf(wB.x, xvk, acc[4]); acc[5] = fmaf(wB.y, xvk, acc[5]);
                acc[6] = fmaf(wB.z, xvk, acc[6]); acc[7] = fmaf(wB.w, xvk, acc[7]);
            }
        }
    }
}

__global__ __launch_bounds__(256) void conv3_cuba(const float* __restrict__ s2,
                                                  const float* __restrict__ wT,
                                                  float* __restrict__ s3) {
    __shared__ float red[4][8][68];
    const int wid = RFL(threadIdx.x >> 6), t = threadIdx.x & 63;
    const int og = RFL(blockIdx.x) & 7;
    const int spi = (RFL(blockIdx.x) >> 3) & 3;
    const int b = RFL(blockIdx.x) >> 5;

    float acc[8];
#pragma unroll
    for (int j = 0; j < 8; j++) acc[j] = 0.f;
    const float* xb = s2 + (size_t)b * 32 * 8 * 8 * TT + t;
    const float* wTo = wT + og * 8;

    switch (spi) {
        case 0: conv3_acc<0, 0>(xb, wTo, wid, acc); break;
        case 1: conv3_acc<0, 1>(xb, wTo, wid, acc); break;
        case 2: conv3_acc<1, 0>(xb, wTo, wid, acc); break;
        default: conv3_acc<1, 1>(xb, wTo, wid, acc); break;
    }
#pragma unroll
    for (int j = 0; j < 8; j++) red[wid][j][t] = acc[j];
    __syncthreads();
    if (wid == 0) {
#pragma unroll
        for (int j = 0; j < 8; j++)
            red[0][j][t] = ((red[0][j][t] + red[1][j][t]) + red[2][j][t]) + red[3][j][t];
    }
    __syncthreads();
    if (threadIdx.x < 8) {
        const int j = threadIdx.x;
        const float* row = &red[0][j][0];
        float4* op = (float4*)(s3 + ((size_t)b * 256 + og * 32 + j * 4 + spi) * TT);
        float c = 0.f, v = 0.f;
        for (int tc = 0; tc < 4; tc++) {
            float4 r0 = *(const float4*)&row[tc * 16 + 0];
            float4 r1 = *(const float4*)&row[tc * 16 + 4];
            float4 r2 = *(const float4*)&row[tc * 16 + 8];
            float4 r3 = *(const float4*)&row[tc * 16 + 12];
            scan4(c, v, r0); scan4(c, v, r1); scan4(c, v, r2); scan4(c, v, r3);
            op[tc * 4 + 0] = r0; op[tc * 4 + 1] = r1;
            op[tc * 4 + 2] = r2; op[tc * 4 + 3] = r3;
        }
    }
}

// ---------------- dense1 (256 -> 2056) fused with CUBA ----------------------
__global__ __launch_bounds__(256) void dense1_cuba(const float* __restrict__ s3,
                                                   const float* __restrict__ w,
                                                   float* __restrict__ s4) {
    __shared__ float lds[4][8][68];
    const int wid = threadIdx.x >> 6, t = threadIdx.x & 63;
    const int task = blockIdx.x * 4 + wid;  // 0..4111  (16 b x 257 og)
    const int bq = task / 257;
    const int ogq = task - bq * 257;
    const int b = RFL(bq);
    const int o0 = RFL(ogq * 8);

    float a0=0,a1=0,a2=0,a3=0,a4=0,a5=0,a6=0,a7=0;
    const float* ab = s3 + (size_t)b * 256 * TT + t;
    const float* r0 = w + (size_t)(o0 + 0) * 256;
    const float* r1 = w + (size_t)(o0 + 1) * 256;
    const float* r2 = w + (size_t)(o0 + 2) * 256;
    const float* r3 = w + (size_t)(o0 + 3) * 256;
    const float* r4 = w + (size_t)(o0 + 4) * 256;
    const float* r5 = w + (size_t)(o0 + 5) * 256;
    const float* r6 = w + (size_t)(o0 + 6) * 256;
    const float* r7 = w + (size_t)(o0 + 7) * 256;

#pragma unroll 2
    for (int i = 0; i < 256; i += 4) {
        const float av0 = ab[(size_t)(i + 0) * TT];
        const float av1 = ab[(size_t)(i + 1) * TT];
        const float av2 = ab[(size_t)(i + 2) * TT];
        const float av3 = ab[(size_t)(i + 3) * TT];
        const float4 q0 = *(const float4*)(r0 + i);
        const float4 q1 = *(const float4*)(r1 + i);
        const float4 q2 = *(const float4*)(r2 + i);
        const float4 q3 = *(const float4*)(r3 + i);
        const float4 q4 = *(const float4*)(r4 + i);
        const float4 q5 = *(const float4*)(r5 + i);
        const float4 q6 = *(const float4*)(r6 + i);
        const float4 q7 = *(const float4*)(r7 + i);
        a0 = fmaf(q0.x, av0, a0); a1 = fmaf(q1.x, av0, a1);
        a2 = fmaf(q2.x, av0, a2); a3 = fmaf(q3.x, av0, a3);
        a4 = fmaf(q4.x, av0, a4); a5 = fmaf(q5.x, av0, a5);
        a6 = fmaf(q6.x, av0, a6); a7 = fmaf(q7.x, av0, a7);
        a0 = fmaf(q0.y, av1, a0); a1 = fmaf(q1.y, av1, a1);
        a2 = fmaf(q2.y, av1, a2); a3 = fmaf(q3.y, av1, a3);
        a4 = fmaf(q4.y, av1, a4); a5 = fmaf(q5.y, av1, a5);
        a6 = fmaf(q6.y, av1, a6); a7 = fmaf(q7.y, av1, a7);
        a0 = fmaf(q0.z, av2, a0); a1 = fmaf(q1.z, av2, a1);
        a2 = fmaf(q2.z, av2, a2); a3 = fmaf(q3.z, av2, a3);
        a4 = fmaf(q4.z, av2, a4); a5 = fmaf(q5.z, av2, a5);
        a6 = fmaf(q6.z, av2, a6); a7 = fmaf(q7.z, av2, a7);
        a0 = fmaf(q0.w, av3, a0); a1 = fmaf(q1.w, av3, a1);
        a2 = fmaf(q2.w, av3, a2); a3 = fmaf(q3.w, av3, a3);
        a4 = fmaf(q4.w, av3, a4); a5 = fmaf(q5.w, av3, a5);
        a6 = fmaf(q6.w, av3, a6); a7 = fmaf(q7.w, av3, a7);
    }
    lds[wid][0][t] = a0; lds[wid][1][t] = a1; lds[wid][2][t] = a2; lds[wid][3][t] = a3;
    lds[wid][4][t] = a4; lds[wid][5][t] = a5; lds[wid][6][t] = a6; lds[wid][7][t] = a7;
    __syncthreads();
    if (t < 8) {
        const float* row = &lds[wid][t][0];
        float4* op = (float4*)(s4 + ((size_t)b * 2056 + o0 + t) * TT);
        float c = 0.f, v = 0.f;
        for (int tc = 0; tc < 4; tc++) {
            float4 r0q = *(const float4*)&row[tc * 16 + 0];
            float4 r1q = *(const float4*)&row[tc * 16 + 4];
            float4 r2q = *(const float4*)&row[tc * 16 + 8];
            float4 r3q = *(const float4*)&row[tc * 16 + 12];
            scan4(c, v, r0q); scan4(c, v, r1q); scan4(c, v, r2q); scan4(c, v, r3q);
            op[tc * 4 + 0] = r0q; op[tc * 4 + 1] = r1q;
            op[tc * 4 + 2] = r2q; op[tc * 4 + 3] = r3q;
        }
    }
}

// ---------------- dense2 stage 1: split-K partial sums ----------------------
__global__ __launch_bounds__(256) void dense2_part(const float* __restrict__ s4,
                                                   const float* __restrict__ wP,
                                                   float* __restrict__ z4p) {
    __shared__ float red[4][11][64];
    const int sp = blockIdx.x, b = blockIdx.y;
    const int w = threadIdx.x >> 6, t = threadIdx.x & 63;
    const int i0 = sp * 257, iend = i0 + 257;  // 2056 = 8*257
    const float* src = s4 + (size_t)b * 2056 * TT + t;

    float acc[11];
#pragma unroll
    for (int j = 0; j < 11; j++) acc[j] = 0.f;

    for (int i = i0 + w; i < iend; i += 4) {
        const float xv = src[(size_t)i * TT];
        const float4* wp = (const float4*)(wP + (size_t)i * 12);
        const float4 w0 = wp[0], w1 = wp[1], w2 = wp[2];
        acc[0]  = fmaf(w0.x, xv, acc[0]);  acc[1]  = fmaf(w0.y, xv, acc[1]);
        acc[2]  = fmaf(w0.z, xv, acc[2]);  acc[3]  = fmaf(w0.w, xv, acc[3]);
        acc[4]  = fmaf(w1.x, xv, acc[4]);  acc[5]  = fmaf(w1.y, xv, acc[5]);
        acc[6]  = fmaf(w1.z, xv, acc[6]);  acc[7]  = fmaf(w1.w, xv, acc[7]);
        acc[8]  = fmaf(w2.x, xv, acc[8]);  acc[9]  = fmaf(w2.y, xv, acc[9]);
        acc[10] = fmaf(w2.z, xv, acc[10]);
    }
#pragma unroll
    for (int j = 0; j < 11; j++) red[w][j][t] = acc[j];
    __syncthreads();
    if (w == 0) {
#pragma unroll
        for (int j = 0; j < 11; j++) {
            const float s = red[0][j][t] + red[1][j][t] + red[2][j][t] + red[3][j][t];
            z4p[(((size_t)b * 8 + sp) * 11 + j) * TT + t] = s;
        }
    }
}

// ---------------- dense2 stage 2: fixed-order reduce + final CUBA scan ------
__global__ __launch_bounds__(256) void dense2_scan(const float* __restrict__ z4p,
                                                   float* __restrict__ out) {
    __shared__ float z[11][64];
    const int b = blockIdx.x;
    for (int idx = threadIdx.x; idx < 11 * 64; idx += 256) {
        const int o = idx >> 6, t = idx & 63;
        float s = 0.f;
#pragma unroll
        for (int sp = 0; sp < 8; sp++)
            s += z4p[(((size_t)b * 8 + sp) * 11 + o) * TT + t];
        z[o][t] = s;
    }
    __syncthreads();
    if (threadIdx.x < 11) {
        const int o = threadIdx.x;
        float c = 0.f, v = 0.f;
        float* op = out + ((size_t)b * 11 + o) * TT;
#pragma unroll
        for (int t = 0; t < TT; t++) {
            float zz = z[o][t];
            scanc(c, v, zz);
            op[t] = zz;
        }
    }
}

extern "C" void kernel_launch(void* const* d_in, const int* in_sizes, int n_in,
                              void* d_out, int out_size, void* d_ws, size_t ws_size,
                              hipStream_t stream) {
    const float* x   = (const float*)d_in[0];
    const float* c1v = (const float*)d_in[1];  const float* c1g = (const float*)d_in[2];
    const float* c2v = (const float*)d_in[3];  const float* c2g = (const float*)d_in[4];
    const float* c3v = (const float*)d_in[5];  const float* c3g = (const float*)d_in[6];
    const float* d1v = (const float*)d_in[7];  const float* d1g = (const float*)d_in[8];
    const float* d2v = (const float*)d_in[9];  const float* d2g = (const float*)d_in[10];

    float* ws = (float*)d_ws;
    // weight region
    float* w1T  = ws + 0;        // (50,8)     = 400
    float* w2T  = ws + 400;      // (200,32)   = 6400
    float* w3T  = ws + 6800;     // (800,64)   = 51200
    float* wd1  = ws + 58000;    // (2056,256) original layout = 526336
    float* wd2P = ws + 584336;   // (2056,12) padded = 24672
    // activation regions
    float* A = ws + 609008;
    float* B = A + 8388608;
    float* s3  = A;              // dense-in spikes (b,256,t)
    float* s4  = A + 262144;     // dense1 spikes (b,2056,t)
    float* s2  = B;              // conv2 spikes (b,32,8,8,t)
    float* z4p = B + 2097152;    // dense2 partials (b,8,11,t)
    // bitmask regions (8B-aligned: float offsets are even)
    u64* xbits  = (u64*)(ws + 13191920);  // 524288 u64 = 4 MB
    u64* s1bits = (u64*)(ws + 14240496);  // 131072 u64 = 1 MB
    (void)ws_size; (void)in_sizes; (void)n_in; (void)out_size;

    wnorm_all<<<dim3(2171), dim3(256), 0, stream>>>(c1v, c1g, w1T, c2v, c2g, w2T,
                                                    c3v, c3g, w3T, d1v, d1g, wd1,
                                                    d2v, d2g, wd2P);
    pack_x<<<dim3(2048), dim3(256), 0, stream>>>(x, xbits);

    conv1_cuba <<<dim3(4096), dim3(256), 0, stream>>>(xbits, w1T, s1bits);
    conv2_cuba <<<dim3(512),  dim3(256), 0, stream>>>(s1bits, w2T, s2);
    conv3_cuba <<<dim3(512),  dim3(256), 0, stream>>>(s2, w3T, s3);
    dense1_cuba<<<dim3(1028), dim3(256), 0, stream>>>(s3, wd1, s4);
    dense2_part<<<dim3(8, 16), dim3(256), 0, stream>>>(s4, wd2P, z4p);
    dense2_scan<<<dim3(16),   dim3(256), 0, stream>>>(z4p, (float*)d_out);
}

// Round 12
// 153.138 us; speedup vs baseline: 1.2866x; 1.1138x over previous
//
#include <hip/hip_runtime.h>
#include <cstddef>

#define TT 64  // timesteps

#define RFL(x) __builtin_amdgcn_readfirstlane(x)

typedef unsigned long long u64;

// ---------------- CUBA LIF step helpers ----------------
__device__ __forceinline__ void scanc(float& c, float& v, float& z) {
    c = fmaf(0.7f, c, z);
    v = fmaf(0.75f, v, c);
    float s = (v >= 1.0f) ? 1.0f : 0.0f;
    v = (v >= 1.0f) ? 0.0f : v;
    z = s;
}
__device__ __forceinline__ void scan4(float& c, float& v, float4& a) {
    scanc(c, v, a.x); scanc(c, v, a.y); scanc(c, v, a.z); scanc(c, v, a.w);
}
__device__ __forceinline__ float bit2f(u64 m, int t) {
    return (float)((m >> t) & 1ULL);  // exactly 0.0f or 1.0f
}

// ---------------- prep: all weight_norms + x-packing in ONE dispatch --------
// Blocks 0..2170: weight_norm segments (identical math to previous rounds).
// Blocks 2171..6266: pack x into per-pixel time bitmasks — 16-lane group per
// pixel, 2 pixels per thread per iteration (loads issued before the shfl
// chains -> 2x memory-level parallelism). Bit t == (x[t] > 0.5), same layout.
__global__ __launch_bounds__(256) void prep(
    const float* __restrict__ c1v, const float* __restrict__ c1g, float* __restrict__ w1T,
    const float* __restrict__ c2v, const float* __restrict__ c2g, float* __restrict__ w2T,
    const float* __restrict__ c3v, const float* __restrict__ c3g, float* __restrict__ w3T,
    const float* __restrict__ d1v, const float* __restrict__ d1g, float* __restrict__ wd1,
    const float* __restrict__ d2v, const float* __restrict__ d2g, float* __restrict__ wd2P,
    const float* __restrict__ x, u64* __restrict__ xb) {
    __shared__ float red[256];
    const int bid = blockIdx.x;
    if (bid >= 2171) {  // ---- pack path ----
        const int sub = threadIdx.x & 15;
        const int grp = threadIdx.x >> 4;  // 16 pixel-slots
        const int pb = bid - 2171;         // 0..4095
#pragma unroll
        for (int it = 0; it < 4; it++) {
            const size_t base = ((size_t)pb * 4 + it) * 32;  // 32 pixels/iter
            const size_t p0 = base + grp;
            const size_t p1 = base + 16 + grp;
            const float4 v0 = *(const float4*)(x + p0 * TT + sub * 4);
            const float4 v1 = *(const float4*)(x + p1 * TT + sub * 4);
            const unsigned int n0 = (v0.x > 0.5f ? 1u : 0u) | (v0.y > 0.5f ? 2u : 0u) |
                                    (v0.z > 0.5f ? 4u : 0u) | (v0.w > 0.5f ? 8u : 0u);
            const unsigned int n1 = (v1.x > 0.5f ? 1u : 0u) | (v1.y > 0.5f ? 2u : 0u) |
                                    (v1.z > 0.5f ? 4u : 0u) | (v1.w > 0.5f ? 8u : 0u);
            u64 w0 = (u64)n0 << (4 * sub);
            u64 w1 = (u64)n1 << (4 * sub);
            w0 |= __shfl_xor(w0, 1); w1 |= __shfl_xor(w1, 1);
            w0 |= __shfl_xor(w0, 2); w1 |= __shfl_xor(w1, 2);
            w0 |= __shfl_xor(w0, 4); w1 |= __shfl_xor(w1, 4);
            w0 |= __shfl_xor(w0, 8); w1 |= __shfl_xor(w1, 8);
            if (sub == 0) { xb[p0] = w0; xb[p1] = w1; }
        }
        return;
    }
    // ---- weight_norm path ----
    const float *v, *g; float* w; int o, K, LD; bool tr;
    if (bid < 8)         { v = c1v; g = c1g; w = w1T;  o = bid;        K = 50;   LD = 8;  tr = true;  }
    else if (bid < 40)   { v = c2v; g = c2g; w = w2T;  o = bid - 8;    K = 200;  LD = 32; tr = true;  }
    else if (bid < 104)  { v = c3v; g = c3g; w = w3T;  o = bid - 40;   K = 800;  LD = 64; tr = true;  }
    else if (bid < 2160) { v = d1v; g = d1g; w = wd1;  o = bid - 104;  K = 256;  LD = 0;  tr = false; }
    else                 { v = d2v; g = d2g; w = wd2P; o = bid - 2160; K = 2056; LD = 12; tr = true;  }

    float s = 0.f;
    for (int k = threadIdx.x; k < K; k += 256) {
        float xx = v[(size_t)o * K + k];
        s += xx * xx;
    }
    red[threadIdx.x] = s;
    __syncthreads();
    for (int off = 128; off > 0; off >>= 1) {
        if (threadIdx.x < off) red[threadIdx.x] += red[threadIdx.x + off];
        __syncthreads();
    }
    const float scale = g[o] / sqrtf(red[0]);
    for (int k = threadIdx.x; k < K; k += 256) {
        float val = scale * v[(size_t)o * K + k];
        if (tr) w[(size_t)k * LD + o] = val;
        else    w[(size_t)o * K + k] = val;
    }
}

// ---------------- conv1 (2->8) on bitmasks, fused CUBA, bitmask out ---------
__global__ __launch_bounds__(256) void conv1_cuba(const u64* __restrict__ xb,
                                                  const float* __restrict__ w1T,
                                                  u64* __restrict__ s1b) {
    __shared__ float lds[4][8][68];
    const int wid = RFL(threadIdx.x >> 6), t = threadIdx.x & 63;
    const int task = RFL(blockIdx.x) * 4 + wid;  // 0..16383
    const int spi = task & 1023, b = task >> 10;
    const int oy = spi >> 5, ox = spi & 31;

    float a0=0,a1=0,a2=0,a3=0,a4=0,a5=0,a6=0,a7=0;
    const u64* xq = xb + (size_t)b * 2 * 16384;

    if (oy >= 1 && ox >= 1) {
        const u64* xi = xq + (size_t)(oy * 4 - 1) * 128 + (ox * 4 - 1);
        for (int ci = 0; ci < 2; ci++) {
            u64 m[25];
#pragma unroll
            for (int ky = 0; ky < 5; ky++)
#pragma unroll
                for (int kx = 0; kx < 5; kx++)
                    m[ky * 5 + kx] = xi[ci * 16384 + ky * 128 + kx];
#pragma unroll
            for (int k = 0; k < 25; k++) {
                const float xvk = bit2f(m[k], t);
                const float4* wp = (const float4*)(w1T + (ci * 25 + k) * 8);
                const float4 wA = wp[0], wB = wp[1];
                a0 = fmaf(wA.x, xvk, a0); a1 = fmaf(wA.y, xvk, a1);
                a2 = fmaf(wA.z, xvk, a2); a3 = fmaf(wA.w, xvk, a3);
                a4 = fmaf(wB.x, xvk, a4); a5 = fmaf(wB.y, xvk, a5);
                a6 = fmaf(wB.z, xvk, a6); a7 = fmaf(wB.w, xvk, a7);
            }
        }
    } else {
        for (int ci = 0; ci < 2; ci++) {
#pragma unroll
            for (int ky = 0; ky < 5; ky++) {
                const int iy = oy * 4 + ky - 1;
                if (iy < 0 || iy >= 128) continue;
#pragma unroll
                for (int kx = 0; kx < 5; kx++) {
                    const int ix = ox * 4 + kx - 1;
                    if (ix < 0 || ix >= 128) continue;
                    const float xvk = bit2f(xq[ci * 16384 + iy * 128 + ix], t);
                    const float4* wp = (const float4*)(w1T + (ci * 25 + ky * 5 + kx) * 8);
                    const float4 wA = wp[0], wB = wp[1];
                    a0 = fmaf(wA.x, xvk, a0); a1 = fmaf(wA.y, xvk, a1);
                    a2 = fmaf(wA.z, xvk, a2); a3 = fmaf(wA.w, xvk, a3);
                    a4 = fmaf(wB.x, xvk, a4); a5 = fmaf(wB.y, xvk, a5);
                    a6 = fmaf(wB.z, xvk, a6); a7 = fmaf(wB.w, xvk, a7);
                }
            }
        }
    }
    lds[wid][0][t] = a0; lds[wid][1][t] = a1; lds[wid][2][t] = a2; lds[wid][3][t] = a3;
    lds[wid][4][t] = a4; lds[wid][5][t] = a5; lds[wid][6][t] = a6; lds[wid][7][t] = a7;
    __syncthreads();
    if (t < 8) {  // scan channel t in-register, write spikes back to LDS
        float* row = &lds[wid][t][0];
        float c = 0.f, v = 0.f;
        for (int tc = 0; tc < 4; tc++) {
            float4 r0 = *(const float4*)&row[tc * 16 + 0];
            float4 r1 = *(const float4*)&row[tc * 16 + 4];
            float4 r2 = *(const float4*)&row[tc * 16 + 8];
            float4 r3 = *(const float4*)&row[tc * 16 + 12];
            scan4(c, v, r0); scan4(c, v, r1); scan4(c, v, r2); scan4(c, v, r3);
            *(float4*)&row[tc * 16 + 0] = r0; *(float4*)&row[tc * 16 + 4] = r1;
            *(float4*)&row[tc * 16 + 8] = r2; *(float4*)&row[tc * 16 + 12] = r3;
        }
    }
    __syncthreads();
    u64* ob = s1b + (size_t)b * 8 * 1024 + spi;
#pragma unroll
    for (int ch = 0; ch < 8; ch++) {
        const u64 m = __ballot(lds[wid][ch][t] > 0.5f);
        if (t == 0) ob[(size_t)ch * 1024] = m;
    }
}

// ---------------- conv2 (8->32) on bitmasks, fused CUBA, float out ----------
__global__ __launch_bounds__(256) void conv2_cuba(const u64* __restrict__ s1b,
                                                  const float* __restrict__ w2T,
                                                  float* __restrict__ s2) {
    __shared__ float lds[4][16][68];
    const int wid = RFL(threadIdx.x >> 6), t = threadIdx.x & 63;
    const int task = RFL(blockIdx.x) * 4 + wid;  // 0..2047
    const int og = task & 1;
    const int spi = (task >> 1) & 63;
    const int b = task >> 7;
    const int oy = spi >> 3, ox = spi & 7;

    float a[16];
#pragma unroll
    for (int j = 0; j < 16; j++) a[j] = 0.f;
    const u64* sb = s1b + (size_t)b * 8 * 1024;

    if (oy >= 1 && ox >= 1) {
        const u64* si = sb + (size_t)(oy * 4 - 1) * 32 + (ox * 4 - 1);
        for (int ci = 0; ci < 8; ci++) {
            u64 m[25];
#pragma unroll
            for (int ky = 0; ky < 5; ky++)
#pragma unroll
                for (int kx = 0; kx < 5; kx++)
                    m[ky * 5 + kx] = si[ci * 1024 + ky * 32 + kx];
#pragma unroll
            for (int k = 0; k < 25; k++) {
                const float xvk = bit2f(m[k], t);
                const float4* wp = (const float4*)(w2T + (ci * 25 + k) * 32 + og * 16);
                const float4 w0 = wp[0], w1 = wp[1], w2 = wp[2], w3 = wp[3];
                a[0]  = fmaf(w0.x, xvk, a[0]);  a[1]  = fmaf(w0.y, xvk, a[1]);
                a[2]  = fmaf(w0.z, xvk, a[2]);  a[3]  = fmaf(w0.w, xvk, a[3]);
                a[4]  = fmaf(w1.x, xvk, a[4]);  a[5]  = fmaf(w1.y, xvk, a[5]);
                a[6]  = fmaf(w1.z, xvk, a[6]);  a[7]  = fmaf(w1.w, xvk, a[7]);
                a[8]  = fmaf(w2.x, xvk, a[8]);  a[9]  = fmaf(w2.y, xvk, a[9]);
                a[10] = fmaf(w2.z, xvk, a[10]); a[11] = fmaf(w2.w, xvk, a[11]);
                a[12] = fmaf(w3.x, xvk, a[12]); a[13] = fmaf(w3.y, xvk, a[13]);
                a[14] = fmaf(w3.z, xvk, a[14]); a[15] = fmaf(w3.w, xvk, a[15]);
            }
        }
    } else {
        for (int ci = 0; ci < 8; ci++) {
#pragma unroll
            for (int ky = 0; ky < 5; ky++) {
                const int iy = oy * 4 + ky - 1;
                if (iy < 0 || iy >= 32) continue;
#pragma unroll
                for (int kx = 0; kx < 5; kx++) {
                    const int ix = ox * 4 + kx - 1;
                    if (ix < 0 || ix >= 32) continue;
                    const float xvk = bit2f(sb[ci * 1024 + iy * 32 + ix], t);
                    const float4* wp =
                        (const float4*)(w2T + (ci * 25 + ky * 5 + kx) * 32 + og * 16);
                    const float4 w0 = wp[0], w1 = wp[1], w2 = wp[2], w3 = wp[3];
                    a[0]  = fmaf(w0.x, xvk, a[0]);  a[1]  = fmaf(w0.y, xvk, a[1]);
                    a[2]  = fmaf(w0.z, xvk, a[2]);  a[3]  = fmaf(w0.w, xvk, a[3]);
                    a[4]  = fmaf(w1.x, xvk, a[4]);  a[5]  = fmaf(w1.y, xvk, a[5]);
                    a[6]  = fmaf(w1.z, xvk, a[6]);  a[7]  = fmaf(w1.w, xvk, a[7]);
                    a[8]  = fmaf(w2.x, xvk, a[8]);  a[9]  = fmaf(w2.y, xvk, a[9]);
                    a[10] = fmaf(w2.z, xvk, a[10]); a[11] = fmaf(w2.w, xvk, a[11]);
                    a[12] = fmaf(w3.x, xvk, a[12]); a[13] = fmaf(w3.y, xvk, a[13]);
                    a[14] = fmaf(w3.z, xvk, a[14]); a[15] = fmaf(w3.w, xvk, a[15]);
                }
            }
        }
    }
#pragma unroll
    for (int j = 0; j < 16; j++) lds[wid][j][t] = a[j];
    __syncthreads();
    if (t < 16) {
        const float* row = &lds[wid][t][0];
        float4* op = (float4*)(s2 + (((size_t)b * 32 + og * 16 + t) * 64 + spi) * TT);
        float c = 0.f, v = 0.f;
        for (int tc = 0; tc < 4; tc++) {
            float4 r0 = *(const float4*)&row[tc * 16 + 0];
            float4 r1 = *(const float4*)&row[tc * 16 + 4];
            float4 r2 = *(const float4*)&row[tc * 16 + 8];
            float4 r3 = *(const float4*)&row[tc * 16 + 12];
            scan4(c, v, r0); scan4(c, v, r1); scan4(c, v, r2); scan4(c, v, r3);
            op[tc * 4 + 0] = r0; op[tc * 4 + 1] = r1;
            op[tc * 4 + 2] = r2; op[tc * 4 + 3] = r3;
        }
    }
}

// ---------------- conv3 (32->64) fused with CUBA ----------------------------
template <int OY, int OX>
__device__ __forceinline__ void conv3_acc(const float* __restrict__ xb,
                                          const float* __restrict__ wTo,
                                          int wid, float* __restrict__ acc) {
    constexpr int KY0 = (OY == 0) ? 1 : 0;
    constexpr int KX0 = (OX == 0) ? 1 : 0;
    constexpr int NKY = 5 - KY0;
    constexpr int NKX = 5 - KX0;
    for (int c8 = 0; c8 < 8; c8++) {
        const int ci = wid * 8 + c8;
        float xv[NKY * NKX];
#pragma unroll
        for (int ky = KY0; ky < 5; ky++) {
#pragma unroll
            for (int kx = KX0; kx < 5; kx++) {
                const int iy = OY * 4 + ky - 1;
                const int ix = OX * 4 + kx - 1;
                xv[(ky - KY0) * NKX + (kx - KX0)] =
                    xb[((size_t)((ci * 8 + iy) * 8 + ix)) * TT];
            }
        }
#pragma unroll
        for (int ky = KY0; ky < 5; ky++) {
#pragma unroll
            for (int kx = KX0; kx < 5; kx++) {
                const float xvk = xv[(ky - KY0) * NKX + (kx - KX0)];
                const float4* wp = (const float4*)(wTo + (ci * 25 + ky * 5 + kx) * 64);
                const float4 wA = wp[0], wB = wp[1];
                acc[0] = fmaf(wA.x, xvk, acc[0]); acc[1] = fmaf(wA.y, xvk, acc[1]);
                acc[2] = fmaf(wA.z, xvk, acc[2]); acc[3] = fmaf(wA.w, xvk, acc[3]);
                acc[4] = fmaf(wB.x, xvk, acc[4]); acc[5] = fmaf(wB.y, xvk, acc[5]);
                acc[6] = fmaf(wB.z, xvk, acc[6]); acc[7] = fmaf(wB.w, xvk, acc[7]);
            }
        }
    }
}

__global__ __launch_bounds__(256) void conv3_cuba(const float* __restrict__ s2,
                                                  const float* __restrict__ wT,
                                                  float* __restrict__ s3) {
    __shared__ float red[4][8][68];
    const int wid = RFL(threadIdx.x >> 6), t = threadIdx.x & 63;
    const int og = RFL(blockIdx.x) & 7;
    const int spi = (RFL(blockIdx.x) >> 3) & 3;
    const int b = RFL(blockIdx.x) >> 5;

    float acc[8];
#pragma unroll
    for (int j = 0; j < 8; j++) acc[j] = 0.f;
    const float* xb = s2 + (size_t)b * 32 * 8 * 8 * TT + t;
    const float* wTo = wT + og * 8;

    switch (spi) {
        case 0: conv3_acc<0, 0>(xb, wTo, wid, acc); break;
        case 1: conv3_acc<0, 1>(xb, wTo, wid, acc); break;
        case 2: conv3_acc<1, 0>(xb, wTo, wid, acc); break;
        default: conv3_acc<1, 1>(xb, wTo, wid, acc); break;
    }
#pragma unroll
    for (int j = 0; j < 8; j++) red[wid][j][t] = acc[j];
    __syncthreads();
    if (wid == 0) {
#pragma unroll
        for (int j = 0; j < 8; j++)
            red[0][j][t] = ((red[0][j][t] + red[1][j][t]) + red[2][j][t]) + red[3][j][t];
    }
    __syncthreads();
    if (threadIdx.x < 8) {
        const int j = threadIdx.x;
        const float* row = &red[0][j][0];
        float4* op = (float4*)(s3 + ((size_t)b * 256 + og * 32 + j * 4 + spi) * TT);
        float c = 0.f, v = 0.f;
        for (int tc = 0; tc < 4; tc++) {
            float4 r0 = *(const float4*)&row[tc * 16 + 0];
            float4 r1 = *(const float4*)&row[tc * 16 + 4];
            float4 r2 = *(const float4*)&row[tc * 16 + 8];
            float4 r3 = *(const float4*)&row[tc * 16 + 12];
            scan4(c, v, r0); scan4(c, v, r1); scan4(c, v, r2); scan4(c, v, r3);
            op[tc * 4 + 0] = r0; op[tc * 4 + 1] = r1;
            op[tc * 4 + 2] = r2; op[tc * 4 + 3] = r3;
        }
    }
}

// ---------------- dense1 (256 -> 2056) fused with CUBA ----------------------
__global__ __launch_bounds__(256) void dense1_cuba(const float* __restrict__ s3,
                                                   const float* __restrict__ w,
                                                   float* __restrict__ s4) {
    __shared__ float lds[4][8][68];
    const int wid = threadIdx.x >> 6, t = threadIdx.x & 63;
    const int task = blockIdx.x * 4 + wid;  // 0..4111  (16 b x 257 og)
    const int bq = task / 257;
    const int ogq = task - bq * 257;
    const int b = RFL(bq);
    const int o0 = RFL(ogq * 8);

    float a0=0,a1=0,a2=0,a3=0,a4=0,a5=0,a6=0,a7=0;
    const float* ab = s3 + (size_t)b * 256 * TT + t;
    const float* r0 = w + (size_t)(o0 + 0) * 256;
    const float* r1 = w + (size_t)(o0 + 1) * 256;
    const float* r2 = w + (size_t)(o0 + 2) * 256;
    const float* r3 = w + (size_t)(o0 + 3) * 256;
    const float* r4 = w + (size_t)(o0 + 4) * 256;
    const float* r5 = w + (size_t)(o0 + 5) * 256;
    const float* r6 = w + (size_t)(o0 + 6) * 256;
    const float* r7 = w + (size_t)(o0 + 7) * 256;

#pragma unroll 2
    for (int i = 0; i < 256; i += 4) {
        const float av0 = ab[(size_t)(i + 0) * TT];
        const float av1 = ab[(size_t)(i + 1) * TT];
        const float av2 = ab[(size_t)(i + 2) * TT];
        const float av3 = ab[(size_t)(i + 3) * TT];
        const float4 q0 = *(const float4*)(r0 + i);
        const float4 q1 = *(const float4*)(r1 + i);
        const float4 q2 = *(const float4*)(r2 + i);
        const float4 q3 = *(const float4*)(r3 + i);
        const float4 q4 = *(const float4*)(r4 + i);
        const float4 q5 = *(const float4*)(r5 + i);
        const float4 q6 = *(const float4*)(r6 + i);
        const float4 q7 = *(const float4*)(r7 + i);
        a0 = fmaf(q0.x, av0, a0); a1 = fmaf(q1.x, av0, a1);
        a2 = fmaf(q2.x, av0, a2); a3 = fmaf(q3.x, av0, a3);
        a4 = fmaf(q4.x, av0, a4); a5 = fmaf(q5.x, av0, a5);
        a6 = fmaf(q6.x, av0, a6); a7 = fmaf(q7.x, av0, a7);
        a0 = fmaf(q0.y, av1, a0); a1 = fmaf(q1.y, av1, a1);
        a2 = fmaf(q2.y, av1, a2); a3 = fmaf(q3.y, av1, a3);
        a4 = fmaf(q4.y, av1, a4); a5 = fmaf(q5.y, av1, a5);
        a6 = fmaf(q6.y, av1, a6); a7 = fmaf(q7.y, av1, a7);
        a0 = fmaf(q0.z, av2, a0); a1 = fmaf(q1.z, av2, a1);
        a2 = fmaf(q2.z, av2, a2); a3 = fmaf(q3.z, av2, a3);
        a4 = fmaf(q4.z, av2, a4); a5 = fmaf(q5.z, av2, a5);
        a6 = fmaf(q6.z, av2, a6); a7 = fmaf(q7.z, av2, a7);
        a0 = fmaf(q0.w, av3, a0); a1 = fmaf(q1.w, av3, a1);
        a2 = fmaf(q2.w, av3, a2); a3 = fmaf(q3.w, av3, a3);
        a4 = fmaf(q4.w, av3, a4); a5 = fmaf(q5.w, av3, a5);
        a6 = fmaf(q6.w, av3, a6); a7 = fmaf(q7.w, av3, a7);
    }
    lds[wid][0][t] = a0; lds[wid][1][t] = a1; lds[wid][2][t] = a2; lds[wid][3][t] = a3;
    lds[wid][4][t] = a4; lds[wid][5][t] = a5; lds[wid][6][t] = a6; lds[wid][7][t] = a7;
    __syncthreads();
    if (t < 8) {
        const float* row = &lds[wid][t][0];
        float4* op = (float4*)(s4 + ((size_t)b * 2056 + o0 + t) * TT);
        float c = 0.f, v = 0.f;
        for (int tc = 0; tc < 4; tc++) {
            float4 r0q = *(const float4*)&row[tc * 16 + 0];
            float4 r1q = *(const float4*)&row[tc * 16 + 4];
            float4 r2q = *(const float4*)&row[tc * 16 + 8];
            float4 r3q = *(const float4*)&row[tc * 16 + 12];
            scan4(c, v, r0q); scan4(c, v, r1q); scan4(c, v, r2q); scan4(c, v, r3q);
            op[tc * 4 + 0] = r0q; op[tc * 4 + 1] = r1q;
            op[tc * 4 + 2] = r2q; op[tc * 4 + 3] = r3q;
        }
    }
}

// ---------------- dense2 stage 1: split-K partial sums (16 splits) ----------
// grid (16 sp, 16 b) = 256 blocks (1/CU). Split sp covers i in [sp*129,
// min(sp*129+129, 2056)); wave w takes i = i0+w, i0+w+4, ... Stage 2 sums the
// 16 partials in fixed sp order.
__global__ __launch_bounds__(256) void dense2_part(const float* __restrict__ s4,
                                                   const float* __restrict__ wP,
                                                   float* __restrict__ z4p) {
    __shared__ float red[4][11][64];
    const int sp = blockIdx.x, b = blockIdx.y;
    const int w = threadIdx.x >> 6, t = threadIdx.x & 63;
    const int i0 = sp * 129;
    const int iend = (i0 + 129 < 2056) ? i0 + 129 : 2056;
    const float* src = s4 + (size_t)b * 2056 * TT + t;

    float acc[11];
#pragma unroll
    for (int j = 0; j < 11; j++) acc[j] = 0.f;

#pragma unroll 4
    for (int i = i0 + w; i < iend; i += 4) {
        const float xv = src[(size_t)i * TT];
        const float4* wp = (const float4*)(wP + (size_t)i * 12);
        const float4 w0 = wp[0], w1 = wp[1], w2 = wp[2];
        acc[0]  = fmaf(w0.x, xv, acc[0]);  acc[1]  = fmaf(w0.y, xv, acc[1]);
        acc[2]  = fmaf(w0.z, xv, acc[2]);  acc[3]  = fmaf(w0.w, xv, acc[3]);
        acc[4]  = fmaf(w1.x, xv, acc[4]);  acc[5]  = fmaf(w1.y, xv, acc[5]);
        acc[6]  = fmaf(w1.z, xv, acc[6]);  acc[7]  = fmaf(w1.w, xv, acc[7]);
        acc[8]  = fmaf(w2.x, xv, acc[8]);  acc[9]  = fmaf(w2.y, xv, acc[9]);
        acc[10] = fmaf(w2.z, xv, acc[10]);
    }
#pragma unroll
    for (int j = 0; j < 11; j++) red[w][j][t] = acc[j];
    __syncthreads();
    if (w == 0) {
#pragma unroll
        for (int j = 0; j < 11; j++) {
            const float s = red[0][j][t] + red[1][j][t] + red[2][j][t] + red[3][j][t];
            z4p[(((size_t)b * 16 + sp) * 11 + j) * TT + t] = s;
        }
    }
}

// ---------------- dense2 stage 2: fixed-order reduce + final CUBA scan ------
__global__ __launch_bounds__(256) void dense2_scan(const float* __restrict__ z4p,
                                                   float* __restrict__ out) {
    __shared__ float z[11][64];
    const int b = blockIdx.x;
    for (int idx = threadIdx.x; idx < 11 * 64; idx += 256) {
        const int o = idx >> 6, t = idx & 63;
        float s = 0.f;
#pragma unroll
        for (int sp = 0; sp < 16; sp++)
            s += z4p[(((size_t)b * 16 + sp) * 11 + o) * TT + t];
        z[o][t] = s;
    }
    __syncthreads();
    if (threadIdx.x < 11) {
        const int o = threadIdx.x;
        float c = 0.f, v = 0.f;
        float* op = out + ((size_t)b * 11 + o) * TT;
#pragma unroll
        for (int t = 0; t < TT; t++) {
            float zz = z[o][t];
            scanc(c, v, zz);
            op[t] = zz;
        }
    }
}

extern "C" void kernel_launch(void* const* d_in, const int* in_sizes, int n_in,
                              void* d_out, int out_size, void* d_ws, size_t ws_size,
                              hipStream_t stream) {
    const float* x   = (const float*)d_in[0];
    const float* c1v = (const float*)d_in[1];  const float* c1g = (const float*)d_in[2];
    const float* c2v = (const float*)d_in[3];  const float* c2g = (const float*)d_in[4];
    const float* c3v = (const float*)d_in[5];  const float* c3g = (const float*)d_in[6];
    const float* d1v = (const float*)d_in[7];  const float* d1g = (const float*)d_in[8];
    const float* d2v = (const float*)d_in[9];  const float* d2g = (const float*)d_in[10];

    float* ws = (float*)d_ws;
    // weight region
    float* w1T  = ws + 0;        // (50,8)     = 400
    float* w2T  = ws + 400;      // (200,32)   = 6400
    float* w3T  = ws + 6800;     // (800,64)   = 51200
    float* wd1  = ws + 58000;    // (2056,256) original layout = 526336
    float* wd2P = ws + 584336;   // (2056,12) padded = 24672
    // activation regions
    float* A = ws + 609008;
    float* B = A + 8388608;
    float* s3  = A;              // dense-in spikes (b,256,t)
    float* s4  = A + 262144;     // dense1 spikes (b,2056,t)
    float* s2  = B;              // conv2 spikes (b,32,8,8,t)
    float* z4p = B + 2097152;    // dense2 partials (b,16,11,t) = 180224
    // bitmask regions (8B-aligned: float offsets are even)
    u64* xbits  = (u64*)(ws + 13191920);  // 524288 u64 = 4 MB
    u64* s1bits = (u64*)(ws + 14240496);  // 131072 u64 = 1 MB
    (void)ws_size; (void)in_sizes; (void)n_in; (void)out_size;

    // weight norms + x packing fused into one dispatch
    prep<<<dim3(2171 + 4096), dim3(256), 0, stream>>>(
        c1v, c1g, w1T, c2v, c2g, w2T, c3v, c3g, w3T, d1v, d1g, wd1,
        d2v, d2g, wd2P, x, xbits);

    conv1_cuba <<<dim3(4096),   dim3(256), 0, stream>>>(xbits, w1T, s1bits);
    conv2_cuba <<<dim3(512),    dim3(256), 0, stream>>>(s1bits, w2T, s2);
    conv3_cuba <<<dim3(512),    dim3(256), 0, stream>>>(s2, w3T, s3);
    dense1_cuba<<<dim3(1028),   dim3(256), 0, stream>>>(s3, wd1, s4);
    dense2_part<<<dim3(16, 16), dim3(256), 0, stream>>>(s4, wd2P, z4p);
    dense2_scan<<<dim3(16),     dim3(256), 0, stream>>>(z4p, (float*)d_out);
}